// Round 13
// baseline (192.839 us; speedup 1.0000x reference)
//
#include <hip/hip_runtime.h>
#include <hip/hip_bf16.h>
#include <cstddef>

#define H_ 128
#define W_ 128
#define HW_ 16384
#define C_ 64
#define B_ 8
#define EPS_ 1e-5f

#define TSTRF 68   // f32 tile row stride (floats): 272 B, 16B-aligned
#define OTSTR 72   // offconv tile row stride (shorts)

typedef __attribute__((ext_vector_type(8))) short bf16x8;
typedef __attribute__((ext_vector_type(4))) float f32x4;

__device__ __forceinline__ unsigned short f2bf(float f) {
  __hip_bfloat16 h = __float2bfloat16(f);
  unsigned short u;
  __builtin_memcpy(&u, &h, 2);
  return u;
}
__device__ __forceinline__ float bfl(unsigned short v) {
  return __uint_as_float(((unsigned)v) << 16);
}
// pack 2 f32 -> 1 dword of 2 bf16 (lo = a, hi = b), single HW instruction
__device__ __forceinline__ unsigned cvtpk(float a, float b) {
  unsigned d;
  asm("v_cvt_pk_bf16_f32 %0, %1, %2" : "=v"(d) : "v"(a), "v"(b));
  return d;
}

// ---------------- prep: pack ALL GEMM weights into MFMA fragment order ------
// wf2: deform, k-map k = kk*64 + c (18 slots, no padding).
// offwp: offset conv (slot = kk*2+s, k = c). w1p/w2p: 1x1 convs, BN in w1p.
__global__ __launch_bounds__(256) void prep_kernel(
    const float* __restrict__ dw, const float* __restrict__ offw,
    const float* __restrict__ w1, const float* __restrict__ b1,
    const float* __restrict__ gamma, const float* __restrict__ beta,
    const float* __restrict__ rmean, const float* __restrict__ rvar,
    const float* __restrict__ w2,
    unsigned short* __restrict__ wf2, unsigned short* __restrict__ offwp,
    unsigned short* __restrict__ w1p, unsigned short* __restrict__ w2p,
    float* __restrict__ b1f) {
  int i = blockIdx.x * 256 + threadIdx.x;
  if (i < 36864) {  // deform: 18 sg * 4 og * 64 l * 8 j
    int j = i & 7, l = (i >> 3) & 63, og = (i >> 9) & 3, sg = i >> 11;
    int o = og * 16 + (l & 15);
    int k = sg * 32 + ((l >> 4) << 3) + j;  // 0..575
    int kk = k >> 6, c = k & 63;
    wf2[i] = f2bf(dw[o * 576 + c * 9 + kk]);
  } else if (i < 36864 + 18432) {  // offconv: 18 slot * 2 og * 64 l * 8 j
    int j2 = i - 36864;
    int j = j2 & 7, l = (j2 >> 3) & 63, og = (j2 >> 9) & 1, slot = j2 >> 10;
    int kk = slot >> 1, s = slot & 1;
    int oc = og * 16 + (l & 15);
    int c = s * 32 + ((l >> 4) << 3) + j;
    float v = (oc < 18) ? offw[oc * 576 + c * 9 + kk] : 0.f;
    offwp[j2] = f2bf(v);
  } else if (i < 36864 + 18432 + 4096) {
    int j2 = i - 36864 - 18432;
    int j = j2 & 7, l = (j2 >> 3) & 63, og = (j2 >> 9) & 3, sg = j2 >> 11;
    int o = og * 16 + (l & 15);
    int c = sg * 32 + ((l >> 4) << 3) + j;
    float inv = gamma[o] * rsqrtf(rvar[o] + EPS_);
    w1p[j2] = f2bf(w1[o * 64 + c] * inv);
  } else if (i < 36864 + 18432 + 8192) {
    int j2 = i - 36864 - 18432 - 4096;
    int j = j2 & 7, l = (j2 >> 3) & 63, og = (j2 >> 9) & 3, sg = j2 >> 11;
    int o = og * 16 + (l & 15);
    int c = sg * 32 + ((l >> 4) << 3) + j;
    w2p[j2] = f2bf(w2[o * 64 + c]);
  } else if (i < 36864 + 18432 + 8192 + 64) {
    int o = i - 36864 - 18432 - 8192;
    float inv = gamma[o] * rsqrtf(rvar[o] + EPS_);
    b1f[o] = b1[o] * inv + beta[o] - rmean[o] * inv;
  }
}

// ---------------- avg pool 3x3, vectorized: 4 px / thread ----------------
__global__ __launch_bounds__(256) void avgpool_kernel(const float* __restrict__ xin,
                                                      float* __restrict__ p) {
  int i = blockIdx.x * 256 + threadIdx.x;
  int gi = i * 4;
  int bc = gi >> 14;
  int yx = gi & 16383;
  int y = yx >> 7, x0 = yx & 127;
  const float* q = xin + (size_t)bc * HW_;
  float s0 = 0.f, s1 = 0.f, s2 = 0.f, s3 = 0.f;
#pragma unroll
  for (int dy = -1; dy <= 1; ++dy) {
    int yy = y + dy;
    if ((unsigned)yy < 128u) {
      const float* row = q + yy * W_;
      float4 m = *(const float4*)(row + x0);
      float lft = (x0 > 0) ? row[x0 - 1] : 0.f;
      float rgt = (x0 < 124) ? row[x0 + 4] : 0.f;
      s0 += lft + m.x + m.y;
      s1 += m.x + m.y + m.z;
      s2 += m.y + m.z + m.w;
      s3 += m.z + m.w + rgt;
    }
  }
  *(float4*)(p + gi) = make_float4(s0 * (1.f / 9.f), s1 * (1.f / 9.f),
                                   s2 * (1.f / 9.f), s3 * (1.f / 9.f));
}

// ---------------- offset conv via MFMA: 64 px/block (unchanged R11) ---------
__global__ __launch_bounds__(256, 4) void offconv_kernel(
    const float* __restrict__ p, const unsigned short* __restrict__ offwp,
    const float* __restrict__ offb, float* __restrict__ off) {
  __shared__ __align__(16) unsigned short tile[198 * OTSTR];  // 28512 B
  __shared__ float offT[18 * 64];                             // 4608 B
  int t = threadIdx.x;
  int lane = t & 63, wv = t >> 6;
  int l15 = lane & 15, lp = lane >> 4;
  int blk = blockIdx.x;
  int half = blk & 1;
  int row = blk >> 1;
  int b = row >> 7, y = row & 127;
  int x0 = half * 64;
  const float* pb = p + (size_t)b * C_ * HW_;

#pragma unroll
  for (int it = 0; it < 50; ++it) {
    int idx = it * 256 + t;
    if (idx < 12672) {
      int c = idx / 198;
      int rc = idx - c * 198;
      int r = rc / 66, cx = rc - r * 66;
      int iy = y - 1 + r, ix = x0 - 1 + cx;
      bool v = ((unsigned)iy < 128u) && ((unsigned)ix < 128u);
      float val = v ? pb[(size_t)c * HW_ + iy * W_ + ix] : 0.f;
      tile[rc * OTSTR + c] = v ? f2bf(val) : (unsigned short)0;
    }
  }
  if (t < 198) {
    *(uint2*)(tile + t * OTSTR + 64) = make_uint2(0u, 0u);
    *(uint2*)(tile + t * OTSTR + 68) = make_uint2(0u, 0u);
  }
  __syncthreads();

  int og = wv & 1;
  int oc = og * 16 + l15;
  float bo = offb[min(oc, 17)];
  const bf16x8* ofp = (const bf16x8*)offwp;
#pragma unroll
  for (int pti = 0; pti < 2; ++pti) {
    int pt = (wv >> 1) + pti * 2;
    f32x4 aco = (f32x4){bo, bo, bo, bo};
#pragma unroll
    for (int kk = 0; kk < 9; ++kk) {
      int rowb = (kk / 3) * 66 + (kk % 3) + pt * 16 + l15;
#pragma unroll
      for (int s = 0; s < 2; ++s) {
        bf16x8 a = *(const bf16x8*)(tile + rowb * OTSTR + s * 32 + lp * 8);
        bf16x8 bw = ofp[((kk * 2 + s) * 2 + og) * 64 + lane];
        aco = __builtin_amdgcn_mfma_f32_16x16x32_bf16(a, bw, aco, 0, 0, 0);
      }
    }
    if (oc < 18) {
#pragma unroll
      for (int j = 0; j < 4; ++j) offT[oc * 64 + pt * 16 + lp * 4 + j] = aco[j];
    }
  }
  __syncthreads();

#pragma unroll
  for (int it = 0; it < 5; ++it) {
    int idx = it * 256 + t;
    if (idx < 1152) {
      int oc2 = idx >> 6, px = idx & 63;
      off[(size_t)(b * 18 + oc2) * HW_ + y * W_ + x0 + px] = offT[idx];
    }
  }
}

// ---------------- deform: register-direct A-fragments + fused tail ----------
// Lane (l15,lp) of wave wv computes A[row=l15][k = s*32+lp*8+j] itself:
// kk = s>>1, c = (s&1)*32 + lp*8 + j  (k = kk*64+c; fragment never straddles
// kk). B packed with identical (l,j)->k formula -> exact pairing (R6 proof).
__global__ __launch_bounds__(256, 4) void deform_kernel(
    const float* __restrict__ p, const float* __restrict__ off,
    const unsigned short* __restrict__ wf2, const unsigned short* __restrict__ w1p,
    const unsigned short* __restrict__ w2p, const float* __restrict__ db,
    const float* __restrict__ b1f, const float* __restrict__ b2,
    const float* __restrict__ xin, float* __restrict__ out) {
  __shared__ __align__(16) float tileT[100 * TSTRF];     // 27200 B [rc][c]
  __shared__ __align__(16) float4 cwf[144];              // 2304 B
  __shared__ uchar4 rel4[144];                           // 576 B
  __shared__ int4 ci4[144];                              // 2304 B
  __shared__ __align__(16) unsigned short rTb[16 * 72];  // 2304 B
  __shared__ __align__(16) unsigned short hTb[16 * 72];  // 2304 B
  __shared__ int wOK[4];
  int t = threadIdx.x;
  int lane = t & 63, wv = t >> 6;
  int l15 = lane & 15, lp = lane >> 4;
  int pix0 = blockIdx.x * 16;
  int b = pix0 >> 14;
  int yx0 = pix0 & 16383;
  int y = yx0 >> 7, x0 = yx0 & 127;
  int ty = min(max(y - 2, 0), 123);
  int tx = min(max(x0 - 2, 0), 108);
  const float* pb = p + (size_t)b * C_ * HW_;

  int o_me = wv * 16 + l15;
  int px0 = lp * 4;
  const float4 xv = *(const float4*)(xin + (size_t)(b * C_ + o_me) * HW_ + yx0 + px0);

  // ---- params: thread t<144 -> job (pixl = t&15, kk = t>>4) at index t ----
  bool ok = true;
  if (t < 144) {
    int pixl = t & 15, kk = t >> 4;
    int xx = x0 + pixl;
    const float* ob = off + (size_t)(b * 18 + kk * 2) * HW_ + y * W_ + xx;
    float offy = ob[0];
    float offx = ob[HW_];
    float sy = (float)(y + (kk / 3) - 1) + offy;
    float sx = (float)(xx + (kk % 3) - 1) + offx;
    float fy = floorf(sy), fx = floorf(sx);
    float wy = sy - fy, wx = sx - fx;
    int iy = (int)fy, ix = (int)fx;
    float w[4];
    int id[4], rc[4];
#pragma unroll
    for (int j = 0; j < 4; ++j) {
      int dy = j >> 1, dx = j & 1;
      int yc = iy + dy, xc = ix + dx;
      bool v = ((unsigned)yc < 128u) && ((unsigned)xc < 128u);
      int ycc = min(max(yc, 0), 127), xcc = min(max(xc, 0), 127);
      float wgt = (dy ? wy : 1.f - wy) * (dx ? wx : 1.f - wx);
      w[j] = v ? wgt : 0.f;
      id[j] = ycc * W_ + xcc;
      bool in_tile = (ycc >= ty) && (ycc <= ty + 4) && (xcc >= tx) && (xcc <= tx + 19);
      ok = ok && ((w[j] == 0.f) || in_tile);
      int ry = min(max(ycc - ty, 0), 4);
      int rx = min(max(xcc - tx, 0), 19);
      rc[j] = ry * 20 + rx;
    }
    cwf[t] = make_float4(w[0], w[1], w[2], w[3]);
    rel4[t] = make_uchar4((unsigned char)rc[0], (unsigned char)rc[1],
                          (unsigned char)rc[2], (unsigned char)rc[3]);
    ci4[t] = make_int4(id[0], id[1], id[2], id[3]);
  }
  {
    unsigned long long m = __ballot(ok);
    if (lane == 0) wOK[wv] = (m == ~0ull) ? 1 : 0;
  }

  // ---- stage f32 p-tile [rc][c] (pure copy, clamped origin in-bounds) ----
#pragma unroll
  for (int it = 0; it < 25; ++it) {
    int idx = it * 256 + t;  // c = idx/100, rc = idx%100
    int c = idx / 100;
    int rc = idx - c * 100;
    int r = rc / 20, cx = rc - r * 20;
    tileT[rc * TSTRF + c] = pb[(size_t)c * HW_ + (ty + r) * W_ + tx + cx];
  }
  __syncthreads();

  bool fast = wOK[0] && wOK[1] && wOK[2] && wOK[3];

  // ---- deform GEMM with inline register-direct sampling ----
  f32x4 acc;
  {
    float d = db[o_me];
    acc = (f32x4){d, d, d, d};
  }
  const bf16x8* wfp = (const bf16x8*)wf2;

  if (fast) {
#pragma unroll
    for (int kk = 0; kk < 9; ++kk) {
      float4 w = cwf[kk * 16 + l15];
      uchar4 rl = rel4[kk * 16 + l15];
      const float* r0 = tileT + (int)rl.x * TSTRF;
      const float* r1 = tileT + (int)rl.y * TSTRF;
      const float* r2 = tileT + (int)rl.z * TSTRF;
      const float* r3 = tileT + (int)rl.w * TSTRF;
#pragma unroll
      for (int h = 0; h < 2; ++h) {
        int s = kk * 2 + h;
        int cb = h * 32 + lp * 8;
        float4 a00 = *(const float4*)(r0 + cb);
        float4 a10 = *(const float4*)(r1 + cb);
        float4 a20 = *(const float4*)(r2 + cb);
        float4 a30 = *(const float4*)(r3 + cb);
        float4 a01 = *(const float4*)(r0 + cb + 4);
        float4 a11 = *(const float4*)(r1 + cb + 4);
        float4 a21 = *(const float4*)(r2 + cb + 4);
        float4 a31 = *(const float4*)(r3 + cb + 4);
        float s0 = w.x * a00.x + w.y * a10.x + w.z * a20.x + w.w * a30.x;
        float s1 = w.x * a00.y + w.y * a10.y + w.z * a20.y + w.w * a30.y;
        float s2 = w.x * a00.z + w.y * a10.z + w.z * a20.z + w.w * a30.z;
        float s3 = w.x * a00.w + w.y * a10.w + w.z * a20.w + w.w * a30.w;
        float s4 = w.x * a01.x + w.y * a11.x + w.z * a21.x + w.w * a31.x;
        float s5 = w.x * a01.y + w.y * a11.y + w.z * a21.y + w.w * a31.y;
        float s6 = w.x * a01.z + w.y * a11.z + w.z * a21.z + w.w * a31.z;
        float s7 = w.x * a01.w + w.y * a11.w + w.z * a21.w + w.w * a31.w;
        uint4 au = make_uint4(cvtpk(s0, s1), cvtpk(s2, s3),
                              cvtpk(s4, s5), cvtpk(s6, s7));
        bf16x8 afrag = *reinterpret_cast<bf16x8*>(&au);
        bf16x8 bw = wfp[(s * 4 + wv) * 64 + lane];
        acc = __builtin_amdgcn_mfma_f32_16x16x32_bf16(afrag, bw, acc, 0, 0, 0);
      }
    }
  } else {
#pragma unroll 1
    for (int kk = 0; kk < 9; ++kk) {
      float4 w = cwf[kk * 16 + l15];
      int4 id = ci4[kk * 16 + l15];
#pragma unroll
      for (int h = 0; h < 2; ++h) {
        int s = kk * 2 + h;
        int cb = h * 32 + lp * 8;
        float sv[8];
#pragma unroll
        for (int j = 0; j < 8; ++j) {
          const float* pc = pb + (size_t)(cb + j) * HW_;
          sv[j] = w.x * pc[id.x] + w.y * pc[id.y] + w.z * pc[id.z] + w.w * pc[id.w];
        }
        uint4 au = make_uint4(cvtpk(sv[0], sv[1]), cvtpk(sv[2], sv[3]),
                              cvtpk(sv[4], sv[5]), cvtpk(sv[6], sv[7]));
        bf16x8 afrag = *reinterpret_cast<bf16x8*>(&au);
        bf16x8 bw = wfp[(s * 4 + wv) * 64 + lane];
        acc = __builtin_amdgcn_mfma_f32_16x16x32_bf16(afrag, bw, acc, 0, 0, 0);
      }
    }
  }

  // ---- r -> bf16 LDS [px][o] (verified D layout: px = lp*4+j, col = l15) ----
#pragma unroll
  for (int j = 0; j < 4; ++j) {
    rTb[(px0 + j) * 72 + o_me] = f2bf(acc[j]);
  }
  __syncthreads();

  // ---- conv1 + BN + ReLU + residual ----
  f32x4 acc1;
  {
    float bb = b1f[o_me];
    acc1 = (f32x4){bb, bb, bb, bb};
  }
  const unsigned short* arow1 = rTb + l15 * 72 + (lp << 3);
  const bf16x8* w1f8 = (const bf16x8*)w1p;
#pragma unroll
  for (int s = 0; s < 2; ++s) {
    bf16x8 a = *(const bf16x8*)(arow1 + s * 32);
    bf16x8 bw = w1f8[(s * 4 + wv) * 64 + lane];
    acc1 = __builtin_amdgcn_mfma_f32_16x16x32_bf16(a, bw, acc1, 0, 0, 0);
  }
  float h0 = fmaxf(acc1[0], 0.f) + xv.x;
  float h1 = fmaxf(acc1[1], 0.f) + xv.y;
  float h2 = fmaxf(acc1[2], 0.f) + xv.z;
  float h3 = fmaxf(acc1[3], 0.f) + xv.w;
  hTb[(px0 + 0) * 72 + o_me] = f2bf(h0);
  hTb[(px0 + 1) * 72 + o_me] = f2bf(h1);
  hTb[(px0 + 2) * 72 + o_me] = f2bf(h2);
  hTb[(px0 + 3) * 72 + o_me] = f2bf(h3);
  __syncthreads();

  // ---- conv2 ----
  f32x4 acc2;
  {
    float bo = b2[o_me];
    acc2 = (f32x4){bo, bo, bo, bo};
  }
  const unsigned short* arow2 = hTb + l15 * 72 + (lp << 3);
  const bf16x8* w2f8 = (const bf16x8*)w2p;
#pragma unroll
  for (int s = 0; s < 2; ++s) {
    bf16x8 a = *(const bf16x8*)(arow2 + s * 32);
    bf16x8 bw = w2f8[(s * 4 + wv) * 64 + lane];
    acc2 = __builtin_amdgcn_mfma_f32_16x16x32_bf16(a, bw, acc2, 0, 0, 0);
  }
  *(float4*)(out + (size_t)(b * C_ + o_me) * HW_ + yx0 + px0) =
      make_float4(acc2[0], acc2[1], acc2[2], acc2[3]);
}

extern "C" void kernel_launch(void* const* d_in, const int* in_sizes, int n_in,
                              void* d_out, int out_size, void* d_ws, size_t ws_size,
                              hipStream_t stream) {
  const float* x = (const float*)d_in[0];
  const float* offw = (const float*)d_in[1];
  const float* offb = (const float*)d_in[2];
  const float* dw = (const float*)d_in[3];
  const float* db = (const float*)d_in[4];
  const float* w1 = (const float*)d_in[5];
  const float* b1 = (const float*)d_in[6];
  const float* gamma = (const float*)d_in[7];
  const float* beta = (const float*)d_in[8];
  const float* rmean = (const float*)d_in[9];
  const float* rvar = (const float*)d_in[10];
  const float* w2 = (const float*)d_in[11];
  const float* b2 = (const float*)d_in[12];
  float* out = (float*)d_out;

  float* ws = (float*)d_ws;
  float* p = ws;                        // 8388608 f
  float* off = p + 8388608;             // 2359296 f
  unsigned short* wf2 = (unsigned short*)(off + 2359296);  // 36864 bf16
  unsigned short* offwp = wf2 + 36864;  // 18432 bf16
  unsigned short* w1p = offwp + 18432;  // 4096 bf16
  unsigned short* w2p = w1p + 4096;     // 4096 bf16
  float* b1f = (float*)(w2p + 4096);    // 64 f

  prep_kernel<<<257, 256, 0, stream>>>(dw, offw, w1, b1, gamma, beta, rmean,
                                       rvar, w2, wf2, offwp, w1p, w2p, b1f);
  avgpool_kernel<<<8192, 256, 0, stream>>>(x, p);
  offconv_kernel<<<2048, 256, 0, stream>>>(p, offwp, offb, off);
  deform_kernel<<<8192, 256, 0, stream>>>(p, off, wf2, w1p, w2p, db, b1f, b2,
                                          x, out);
}

// Round 14
// 118.011 us; speedup vs baseline: 1.6341x; 1.6341x over previous
//
#include <hip/hip_runtime.h>
#include <hip/hip_bf16.h>
#include <cstddef>

#define H_ 128
#define W_ 128
#define HW_ 16384
#define C_ 64
#define B_ 8
#define EPS_ 1e-5f

#define KSLOTS 19   // deform GEMM k-slots, k = kk*68 + c (c<64 data, 64..67 pad)
#define ROWS 616    // sAb row stride (shorts)
#define TSTR 72     // deform tile row stride (shorts) = 9 granules of 16B
#define OTSTR 72    // offconv tile row stride (shorts)

typedef __attribute__((ext_vector_type(8))) short bf16x8;
typedef __attribute__((ext_vector_type(4))) float f32x4;

__device__ __forceinline__ unsigned short f2bf(float f) {
  __hip_bfloat16 h = __float2bfloat16(f);
  unsigned short u;
  __builtin_memcpy(&u, &h, 2);
  return u;
}
__device__ __forceinline__ unsigned pack2(float lo, float hi) {
  return (unsigned)f2bf(lo) | ((unsigned)f2bf(hi) << 16);
}
__device__ __forceinline__ float bfl(unsigned short v) {
  return __uint_as_float(((unsigned)v) << 16);
}

// ---------------- prep: pack ALL GEMM weights (R12-identical, proven) -------
__global__ __launch_bounds__(256) void prep_kernel(
    const float* __restrict__ dw, const float* __restrict__ offw,
    const float* __restrict__ w1, const float* __restrict__ b1,
    const float* __restrict__ gamma, const float* __restrict__ beta,
    const float* __restrict__ rmean, const float* __restrict__ rvar,
    const float* __restrict__ w2,
    unsigned short* __restrict__ wf2, unsigned short* __restrict__ offwp,
    unsigned short* __restrict__ w1p, unsigned short* __restrict__ w2p,
    float* __restrict__ b1f) {
  int i = blockIdx.x * 256 + threadIdx.x;
  if (i < 38912) {  // deform: 19 sg * 4 og * 64 l * 8 j, k = kk*68 + c
    int j = i & 7, l = (i >> 3) & 63, og = (i >> 9) & 3, sg = i >> 11;
    int o = og * 16 + (l & 15);
    int k = sg * 32 + ((l >> 4) << 3) + j;
    int kk = k / 68, c = k - kk * 68;
    float v = (c < 64) ? dw[o * 576 + c * 9 + kk] : 0.f;
    wf2[i] = f2bf(v);
  } else if (i < 38912 + 18432) {  // offconv
    int j2 = i - 38912;
    int j = j2 & 7, l = (j2 >> 3) & 63, og = (j2 >> 9) & 1, slot = j2 >> 10;
    int kk = slot >> 1, s = slot & 1;
    int oc = og * 16 + (l & 15);
    int c = s * 32 + ((l >> 4) << 3) + j;
    float v = (oc < 18) ? offw[oc * 576 + c * 9 + kk] : 0.f;
    offwp[j2] = f2bf(v);
  } else if (i < 38912 + 18432 + 4096) {
    int j2 = i - 38912 - 18432;
    int j = j2 & 7, l = (j2 >> 3) & 63, og = (j2 >> 9) & 3, sg = j2 >> 11;
    int o = og * 16 + (l & 15);
    int c = sg * 32 + ((l >> 4) << 3) + j;
    float inv = gamma[o] * rsqrtf(rvar[o] + EPS_);
    w1p[j2] = f2bf(w1[o * 64 + c] * inv);
  } else if (i < 38912 + 18432 + 8192) {
    int j2 = i - 38912 - 18432 - 4096;
    int j = j2 & 7, l = (j2 >> 3) & 63, og = (j2 >> 9) & 3, sg = j2 >> 11;
    int o = og * 16 + (l & 15);
    int c = sg * 32 + ((l >> 4) << 3) + j;
    w2p[j2] = f2bf(w2[o * 64 + c]);
  } else if (i < 38912 + 18432 + 8192 + 64) {
    int o = i - 38912 - 18432 - 8192;
    float inv = gamma[o] * rsqrtf(rvar[o] + EPS_);
    b1f[o] = b1[o] * inv + beta[o] - rmean[o] * inv;
  }
}

// ---------------- avg pool 3x3 -> NHWC bf16 output ----------------
// Block: 64 consecutive pixels (half row), all 64 channels. Thread t:
// channel c = t&63, 16 px starting at (t>>6)*16. LDS transpose -> coalesced
// 16B NHWC writes. Swizzled pool tile (g ^ (px&7)) for conflict-free b128.
__global__ __launch_bounds__(256) void avgpool_kernel(const float* __restrict__ xin,
                                                      unsigned short* __restrict__ pbf) {
  __shared__ __align__(16) unsigned short pool[64 * 72];  // 9216 B
  int t = threadIdx.x;
  int c = t & 63, wvp = t >> 6;
  int blk = blockIdx.x;
  int half = blk & 1;
  int row = blk >> 1;
  int b = row >> 7, y = row & 127;
  int xb = half * 64 + wvp * 16;
  const float* q = xin + (size_t)(b * C_ + c) * HW_;

  float ver[16];
#pragma unroll
  for (int i = 0; i < 16; ++i) ver[i] = 0.f;
#pragma unroll
  for (int dy = -1; dy <= 1; ++dy) {
    int yy = y + dy;
    if ((unsigned)yy < 128u) {
      const float* r = q + yy * W_;
      float m[18];
      m[0] = (xb > 0) ? r[xb - 1] : 0.f;
      float4 v0 = *(const float4*)(r + xb);
      float4 v1 = *(const float4*)(r + xb + 4);
      float4 v2 = *(const float4*)(r + xb + 8);
      float4 v3 = *(const float4*)(r + xb + 12);
      m[1] = v0.x; m[2] = v0.y; m[3] = v0.z; m[4] = v0.w;
      m[5] = v1.x; m[6] = v1.y; m[7] = v1.z; m[8] = v1.w;
      m[9] = v2.x; m[10] = v2.y; m[11] = v2.z; m[12] = v2.w;
      m[13] = v3.x; m[14] = v3.y; m[15] = v3.z; m[16] = v3.w;
      m[17] = (xb < 112) ? r[xb + 16] : 0.f;
#pragma unroll
      for (int i = 0; i < 16; ++i) ver[i] += m[i] + m[i + 1] + m[i + 2];
    }
  }
  int pxb = wvp * 16;
#pragma unroll
  for (int i = 0; i < 16; ++i) {
    int px = pxb + i;
    int cg = c >> 3;
    pool[px * 72 + ((cg ^ (px & 7)) << 3) + (c & 7)] = f2bf(ver[i] * (1.f / 9.f));
  }
  __syncthreads();

  // coalesced NHWC write: 512 chunks of 16B
  size_t base = ((size_t)(b * HW_) + y * W_ + half * 64) * 64;
#pragma unroll
  for (int k = 0; k < 2; ++k) {
    int ch = k * 256 + t;
    int px = ch >> 3, g = ch & 7;
    uint2 v = *(const uint2*)(pool + px * 72 + ((g ^ (px & 7)) << 3));
    uint2 v2 = *(const uint2*)(pool + px * 72 + ((g ^ (px & 7)) << 3) + 4);
    *(uint4*)(pbf + base + px * 64 + g * 8) = make_uint4(v.x, v.y, v2.x, v2.y);
  }
}

// ---------------- offset conv via MFMA (NHWC chunk staging, swizzled) -------
__global__ __launch_bounds__(256, 4) void offconv_kernel(
    const unsigned short* __restrict__ pbf, const unsigned short* __restrict__ offwp,
    const float* __restrict__ offb, float* __restrict__ off) {
  __shared__ __align__(16) unsigned short tile[198 * OTSTR];  // 28512 B
  __shared__ float offT[18 * 64];                             // 4608 B
  int t = threadIdx.x;
  int lane = t & 63, wv = t >> 6;
  int l15 = lane & 15, lp = lane >> 4;
  int blk = blockIdx.x;
  int half = blk & 1;
  int row = blk >> 1;
  int b = row >> 7, y = row & 127;
  int x0 = half * 64;

  // stage: 198 rows x 8 granules = 1584 chunks of 16B from NHWC pbf
#pragma unroll
  for (int it = 0; it < 7; ++it) {
    int ch = it * 256 + t;
    if (ch < 1584) {
      int rc = ch >> 3, g = ch & 7;
      int r = rc / 66, cx = rc - r * 66;
      int iy = y - 1 + r, ix = x0 - 1 + cx;
      uint4 v = make_uint4(0u, 0u, 0u, 0u);
      if (((unsigned)iy < 128u) && ((unsigned)ix < 128u)) {
        v = *(const uint4*)(pbf + ((size_t)(b * HW_) + iy * W_ + ix) * 64 + g * 8);
      }
      *(uint4*)(tile + rc * OTSTR + ((g ^ (rc & 7)) << 3)) = v;
    }
  }
  __syncthreads();

  int og = wv & 1;
  int oc = og * 16 + l15;
  float bo = offb[min(oc, 17)];
  const bf16x8* ofp = (const bf16x8*)offwp;
#pragma unroll
  for (int pti = 0; pti < 2; ++pti) {
    int pt = (wv >> 1) + pti * 2;
    f32x4 aco = (f32x4){bo, bo, bo, bo};
#pragma unroll
    for (int kk = 0; kk < 9; ++kk) {
      int rowb = (kk / 3) * 66 + (kk % 3) + pt * 16 + l15;
#pragma unroll
      for (int s = 0; s < 2; ++s) {
        int ga = s * 4 + lp;
        bf16x8 a = *(const bf16x8*)(tile + rowb * OTSTR + ((ga ^ (rowb & 7)) << 3));
        bf16x8 bw = ofp[((kk * 2 + s) * 2 + og) * 64 + lane];
        aco = __builtin_amdgcn_mfma_f32_16x16x32_bf16(a, bw, aco, 0, 0, 0);
      }
    }
    if (oc < 18) {
#pragma unroll
      for (int j = 0; j < 4; ++j) offT[oc * 64 + pt * 16 + lp * 4 + j] = aco[j];
    }
  }
  __syncthreads();

#pragma unroll
  for (int it = 0; it < 5; ++it) {
    int idx = it * 256 + t;
    if (idx < 1152) {
      int oc2 = idx >> 6, px = idx & 63;
      off[(size_t)(b * 18 + oc2) * HW_ + y * W_ + x0 + px] = offT[idx];
    }
  }
}

// ---------------- deform (R12 structure + NHWC staging + swizzled tile) -----
__global__ __launch_bounds__(256, 4) void deform_kernel(
    const unsigned short* __restrict__ pbf, const float* __restrict__ off,
    const unsigned short* __restrict__ wf2, const unsigned short* __restrict__ w1p,
    const unsigned short* __restrict__ w2p, const float* __restrict__ db,
    const float* __restrict__ b1f, const float* __restrict__ b2,
    const float* __restrict__ xin, float* __restrict__ out) {
  __shared__ __align__(16) unsigned short tileTb[100 * TSTR];  // 14400 B
  __shared__ __align__(16) unsigned short sAb[16 * ROWS];      // 19712 B
  __shared__ __align__(16) unsigned short rTb[16 * 72];        // 2304 B
  __shared__ __align__(16) unsigned short hTb[16 * 72];        // 2304 B
  __shared__ uint2 cwb[144];                                   // 1152 B
  __shared__ uchar4 rel4[144];                                 // 576 B
  __shared__ int ci4[144];                                     // 576 B (pos idx)
  __shared__ int wOK[4];
  int t = threadIdx.x;
  int lane = t & 63, wv = t >> 6;
  int l15 = lane & 15, lp = lane >> 4;
  int pix0 = blockIdx.x * 16;
  int b = pix0 >> 14;
  int yx0 = pix0 & 16383;
  int y = yx0 >> 7, x0 = yx0 & 127;
  int ty = min(max(y - 2, 0), 123);
  int tx = min(max(x0 - 2, 0), 108);
  const unsigned short* pB = pbf + (size_t)(b * HW_) * 64;

  int o_me = wv * 16 + l15;
  int px0 = lp * 4;
  const float4 xv = *(const float4*)(xin + (size_t)(b * C_ + o_me) * HW_ + yx0 + px0);

  // ---- params: thread t<144 -> job (pixl = t&15, kk = t>>4) ----
  bool ok = true;
  int pixl = t & 15, kk = t >> 4;
  bool active = (t < 144);
  if (active) {
    int xx = x0 + pixl;
    const float* ob = off + (size_t)(b * 18 + kk * 2) * HW_ + y * W_ + xx;
    float offy = ob[0];
    float offx = ob[HW_];
    float sy = (float)(y + (kk / 3) - 1) + offy;
    float sx = (float)(xx + (kk % 3) - 1) + offx;
    float fy = floorf(sy), fx = floorf(sx);
    float wy = sy - fy, wx = sx - fx;
    int iy = (int)fy, ix = (int)fx;
    float w[4];
    int rc[4];
    int id0 = 0;
#pragma unroll
    for (int j = 0; j < 4; ++j) {
      int dy = j >> 1, dx = j & 1;
      int yc = iy + dy, xc = ix + dx;
      bool v = ((unsigned)yc < 128u) && ((unsigned)xc < 128u);
      int ycc = min(max(yc, 0), 127), xcc = min(max(xc, 0), 127);
      float wgt = (dy ? wy : 1.f - wy) * (dx ? wx : 1.f - wx);
      w[j] = v ? wgt : 0.f;
      if (j == 0) id0 = ycc * W_ + xcc;
      bool in_tile = (ycc >= ty) && (ycc <= ty + 4) && (xcc >= tx) && (xcc <= tx + 19);
      ok = ok && ((w[j] == 0.f) || in_tile);
      int ry = min(max(ycc - ty, 0), 4);
      int rx = min(max(xcc - tx, 0), 19);
      rc[j] = ry * 20 + rx;
    }
    cwb[t] = make_uint2(pack2(w[0], w[1]), pack2(w[2], w[3]));
    rel4[t] = make_uchar4((unsigned char)rc[0], (unsigned char)rc[1],
                          (unsigned char)rc[2], (unsigned char)rc[3]);
    ci4[t] = id0;
    // zero own k-pad strip in sAb (c = 64..67)
    *(uint2*)(sAb + pixl * ROWS + kk * 68 + 64) = make_uint2(0u, 0u);
  }
  {
    unsigned long long m = __ballot(ok);
    if (lane == 0) wOK[wv] = (m == ~0ull) ? 1 : 0;
  }

  // ---- stage tile: 100 rows x 8 granules = 800 chunks of 16B (NHWC copy) ----
#pragma unroll
  for (int it = 0; it < 3; ++it) {
    int ch = it * 256 + t;  // 0..767
    int rc = ch >> 3, g = ch & 7;
    int r = rc / 20, cx = rc - r * 20;
    uint4 v = *(const uint4*)(pB + ((size_t)((ty + r) * W_ + tx + cx)) * 64 + g * 8);
    *(uint4*)(tileTb + rc * TSTR + ((g ^ (rc & 7)) << 3)) = v;
  }
  if (t < 32) {
    int ch = 768 + t;
    int rc = ch >> 3, g = ch & 7;
    int r = rc / 20, cx = rc - r * 20;
    uint4 v = *(const uint4*)(pB + ((size_t)((ty + r) * W_ + tx + cx)) * 64 + g * 8);
    *(uint4*)(tileTb + rc * TSTR + ((g ^ (rc & 7)) << 3)) = v;
  }
  __syncthreads();

  bool fast = wOK[0] && wOK[1] && wOK[2] && wOK[3];

  // ---- sampling: 288 half-job slots over 256 threads (R12 distribution) ----
  if (fast) {
    auto do_slot = [&](int slot) {
      int job = slot >> 1, hf = slot & 1;
      int jp = job & 15, jk = job >> 4;
      int bg = hf * 4;  // base granule (c0 = hf*32)
      uint2 wp = cwb[job];
      float w0 = bfl((unsigned short)(wp.x & 0xffffu));
      float w1_ = bfl((unsigned short)(wp.x >> 16));
      float w2_ = bfl((unsigned short)(wp.y & 0xffffu));
      float w3_ = bfl((unsigned short)(wp.y >> 16));
      uchar4 rl = rel4[job];
      int r0 = rl.x, r1 = rl.y, r2 = rl.z, r3 = rl.w;
      unsigned short* wr = sAb + jp * ROWS + jk * 68 + hf * 32;
#pragma unroll
      for (int gg = 0; gg < 4; ++gg) {
        int g = bg + gg;
        bf16x8 v0 = *(const bf16x8*)(tileTb + r0 * TSTR + ((g ^ (r0 & 7)) << 3));
        bf16x8 v1 = *(const bf16x8*)(tileTb + r1 * TSTR + ((g ^ (r1 & 7)) << 3));
        bf16x8 v2 = *(const bf16x8*)(tileTb + r2 * TSTR + ((g ^ (r2 & 7)) << 3));
        bf16x8 v3 = *(const bf16x8*)(tileTb + r3 * TSTR + ((g ^ (r3 & 7)) << 3));
        unsigned dws[4];
#pragma unroll
        for (int e = 0; e < 8; e += 2) {
          float lo = w0 * bfl((unsigned short)v0[e]) + w1_ * bfl((unsigned short)v1[e]) +
                     w2_ * bfl((unsigned short)v2[e]) + w3_ * bfl((unsigned short)v3[e]);
          float hi = w0 * bfl((unsigned short)v0[e + 1]) + w1_ * bfl((unsigned short)v1[e + 1]) +
                     w2_ * bfl((unsigned short)v2[e + 1]) + w3_ * bfl((unsigned short)v3[e + 1]);
          dws[e >> 1] = pack2(lo, hi);
        }
        *(uint2*)(wr + gg * 8) = make_uint2(dws[0], dws[1]);
        *(uint2*)(wr + gg * 8 + 4) = make_uint2(dws[2], dws[3]);
      }
    };
    do_slot(t);
    if ((t & 7) == 0) do_slot(256 + (t >> 3));
  } else {
    if (active) {
      // slow path: recompute 4 corner positions, sample NHWC bf16 p globally
      int xx = x0 + pixl;
      const float* ob = off + (size_t)(b * 18 + kk * 2) * HW_ + y * W_ + xx;
      float offy = ob[0];
      float offx = ob[HW_];
      float sy = (float)(y + (kk / 3) - 1) + offy;
      float sx = (float)(xx + (kk % 3) - 1) + offx;
      float fy = floorf(sy), fx = floorf(sx);
      float wy = sy - fy, wx = sx - fx;
      int iy = (int)fy, ix = (int)fx;
      float wj[4];
      const unsigned short* pc[4];
#pragma unroll
      for (int j = 0; j < 4; ++j) {
        int dy = j >> 1, dx = j & 1;
        int yc = iy + dy, xc = ix + dx;
        bool v = ((unsigned)yc < 128u) && ((unsigned)xc < 128u);
        int ycc = min(max(yc, 0), 127), xcc = min(max(xc, 0), 127);
        wj[j] = v ? (dy ? wy : 1.f - wy) * (dx ? wx : 1.f - wx) : 0.f;
        pc[j] = pB + ((size_t)(ycc * W_ + xcc)) * 64;
      }
      unsigned short* wr = sAb + pixl * ROWS + kk * 68;
#pragma unroll 4
      for (int c = 0; c < 64; ++c) {
        float v = wj[0] * bfl(pc[0][c]) + wj[1] * bfl(pc[1][c]) +
                  wj[2] * bfl(pc[2][c]) + wj[3] * bfl(pc[3][c]);
        wr[c] = f2bf(v);
      }
    }
  }
  __syncthreads();

  // ---- deform GEMM: 19 slots (proven A/B pairing + D layout) ----
  f32x4 acc;
  {
    float d = db[o_me];
    acc = (f32x4){d, d, d, d};
  }
  const unsigned short* arow = sAb + l15 * ROWS + (lp << 3);
  const bf16x8* wfp = (const bf16x8*)wf2;
#pragma unroll
  for (int s = 0; s < KSLOTS; ++s) {
    bf16x8 a = *(const bf16x8*)(arow + s * 32);
    bf16x8 bw = wfp[(s * 4 + wv) * 64 + lane];
    acc = __builtin_amdgcn_mfma_f32_16x16x32_bf16(a, bw, acc, 0, 0, 0);
  }

#pragma unroll
  for (int j = 0; j < 4; ++j) {
    rTb[(px0 + j) * 72 + o_me] = f2bf(acc[j]);
  }
  __syncthreads();

  // ---- conv1 + BN + ReLU + residual ----
  f32x4 acc1;
  {
    float bb = b1f[o_me];
    acc1 = (f32x4){bb, bb, bb, bb};
  }
  const unsigned short* arow1 = rTb + l15 * 72 + (lp << 3);
  const bf16x8* w1f8 = (const bf16x8*)w1p;
#pragma unroll
  for (int s = 0; s < 2; ++s) {
    bf16x8 a = *(const bf16x8*)(arow1 + s * 32);
    bf16x8 bw = w1f8[(s * 4 + wv) * 64 + lane];
    acc1 = __builtin_amdgcn_mfma_f32_16x16x32_bf16(a, bw, acc1, 0, 0, 0);
  }
  float h0 = fmaxf(acc1[0], 0.f) + xv.x;
  float h1 = fmaxf(acc1[1], 0.f) + xv.y;
  float h2 = fmaxf(acc1[2], 0.f) + xv.z;
  float h3 = fmaxf(acc1[3], 0.f) + xv.w;
  hTb[(px0 + 0) * 72 + o_me] = f2bf(h0);
  hTb[(px0 + 1) * 72 + o_me] = f2bf(h1);
  hTb[(px0 + 2) * 72 + o_me] = f2bf(h2);
  hTb[(px0 + 3) * 72 + o_me] = f2bf(h3);
  __syncthreads();

  // ---- conv2 ----
  f32x4 acc2;
  {
    float bo = b2[o_me];
    acc2 = (f32x4){bo, bo, bo, bo};
  }
  const unsigned short* arow2 = hTb + l15 * 72 + (lp << 3);
  const bf16x8* w2f8 = (const bf16x8*)w2p;
#pragma unroll
  for (int s = 0; s < 2; ++s) {
    bf16x8 a = *(const bf16x8*)(arow2 + s * 32);
    bf16x8 bw = w2f8[(s * 4 + wv) * 64 + lane];
    acc2 = __builtin_amdgcn_mfma_f32_16x16x32_bf16(a, bw, acc2, 0, 0, 0);
  }
  *(float4*)(out + (size_t)(b * C_ + o_me) * HW_ + yx0 + px0) =
      make_float4(acc2[0], acc2[1], acc2[2], acc2[3]);
}

extern "C" void kernel_launch(void* const* d_in, const int* in_sizes, int n_in,
                              void* d_out, int out_size, void* d_ws, size_t ws_size,
                              hipStream_t stream) {
  const float* x = (const float*)d_in[0];
  const float* offw = (const float*)d_in[1];
  const float* offb = (const float*)d_in[2];
  const float* dw = (const float*)d_in[3];
  const float* db = (const float*)d_in[4];
  const float* w1 = (const float*)d_in[5];
  const float* b1 = (const float*)d_in[6];
  const float* gamma = (const float*)d_in[7];
  const float* beta = (const float*)d_in[8];
  const float* rmean = (const float*)d_in[9];
  const float* rvar = (const float*)d_in[10];
  const float* w2 = (const float*)d_in[11];
  const float* b2 = (const float*)d_in[12];
  float* out = (float*)d_out;

  unsigned short* pbf = (unsigned short*)d_ws;      // 8388608 bf16 (NHWC)
  float* off = (float*)(pbf + 8388608);             // 2359296 f
  unsigned short* wf2 = (unsigned short*)(off + 2359296);  // 38912 bf16
  unsigned short* offwp = wf2 + 38912;              // 18432 bf16
  unsigned short* w1p = offwp + 18432;              // 4096 bf16
  unsigned short* w2p = w1p + 4096;                 // 4096 bf16
  float* b1f = (float*)(w2p + 4096);                // 64 f

  prep_kernel<<<257, 256, 0, stream>>>(dw, offw, w1, b1, gamma, beta, rmean,
                                       rvar, w2, wf2, offwp, w1p, w2p, b1f);
  avgpool_kernel<<<2048, 256, 0, stream>>>(x, pbf);
  offconv_kernel<<<2048, 256, 0, stream>>>(pbf, offwp, offb, off);
  deform_kernel<<<8192, 256, 0, stream>>>(pbf, off, wf2, w1p, w2p, db, b1f, b2,
                                          x, out);
}